// Round 2
// baseline (1201.033 us; speedup 1.0000x reference)
//
#include <hip/hip_runtime.h>
#include <hip/hip_bf16.h>
#include <stdint.h>

#define NB 65536   // batch B
typedef unsigned short u16;
typedef unsigned int u32;

typedef __attribute__((ext_vector_type(8))) short bf16x8;
typedef __attribute__((ext_vector_type(4))) float f32x4;

__device__ __forceinline__ u16 f2bf(float x) {
    u32 u = __float_as_uint(x);
    u32 r = u + 0x7FFFu + ((u >> 16) & 1u);   // RNE
    return (u16)(r >> 16);
}
__device__ __forceinline__ float bf2f(u16 h) {
    return __uint_as_float(((u32)h) << 16);
}

__device__ __forceinline__ void gl_lds16(const void* g, void* lds_dst) {
    __builtin_amdgcn_global_load_lds(
        (const __attribute__((address_space(1))) void*)(uintptr_t)g,
        (__attribute__((address_space(3))) void*)(uintptr_t)lds_dst,
        16, 0, 0);
}

// ---- adj_t: threshold -> f32 out + bf16 transposed copy for GEMM B-operand
__global__ void k_adj(const float* __restrict__ adj, float* __restrict__ out_adj,
                      u16* __restrict__ adjT) {
    int id = blockIdx.x * 256 + threadIdx.x;      // 262144 threads
    float v = adj[id];
    float tv = (fabsf(v) < 1e-4f) ? 0.0f : v;
    out_adj[id] = tv;
    int k = id >> 9, n = id & 511;
    adjT[n * 512 + k] = f2bf(tv);
}

// ---- generic transpose+cast: dst[n*K+k] = bf16(src[k*N+n]), dst is [N][K]
__global__ void k_castT(u16* __restrict__ dst, const float* __restrict__ src,
                        int K, int N) {
    int id = blockIdx.x * 256 + threadIdx.x;
    if (id >= K * N) return;
    int n = id / K, k = id - n * K;
    dst[id] = f2bf(src[k * N + n]);
}

// ---- gather user rows: f32 -> inp output (cols 0..255) + bf16 attr
__global__ void k_gather_user(const int* __restrict__ idx, const float* __restrict__ table,
                              float* __restrict__ inp_out, u16* __restrict__ attr_bf) {
    int t = blockIdx.x * 256 + threadIdx.x;   // NB*64 threads
    int b = t >> 6, j = t & 63;
    if (b >= NB) return;
    int u = idx[b];
    float4 v = *(const float4*)(table + (size_t)u * 256 + j * 4);
    *(float4*)(inp_out + (size_t)b * 512 + j * 4) = v;
    ushort4 h;
    h.x = f2bf(v.x); h.y = f2bf(v.y); h.z = f2bf(v.z); h.w = f2bf(v.w);
    *(ushort4*)(attr_bf + (size_t)b * 256 + j * 4) = h;
}

// ---- bf16 GEMM: C[MxN] = act(A[MxK] @ W[KxN] + bias)
// A is two row-major bf16 regions: cols [0,ka0) from A0, [ka0,K) from A1.
// Wt is W transposed, [N][K] bf16.  Tile 128x128, BK=32, 4 waves (2x2 of 64x64).
template <int ACT>   // 0 none, 1 relu, 2 sigmoid
__global__ __launch_bounds__(256, 2) void k_gemm(
    const u16* __restrict__ A0, int lda0, int ka0,
    const u16* __restrict__ A1, int lda1,
    const u16* __restrict__ Wt, int K,
    const float* __restrict__ bias0, const float* __restrict__ bias1, int bsplit,
    float* __restrict__ Cf, int ldcf, int cfcol0,
    u16* __restrict__ Cb, int ldcb, int cbcol0) {
    __shared__ __align__(16) u16 lds[2][2][4096];   // [buf][A/B][128*32]
    const int t = threadIdx.x;
    const int w = t >> 6, l = t & 63;
    const int bm = blockIdx.x << 7;
    const int bn = blockIdx.y << 7;
    const int wr = w >> 1, wc = w & 1;
    const int srow = (w << 4) + (l >> 2);   // staging row within 64-row half
    const int scol = (l & 3) << 3;          // staging col (elems)

    f32x4 acc[4][4];
#pragma unroll
    for (int m = 0; m < 4; ++m)
#pragma unroll
        for (int n = 0; n < 4; ++n)
#pragma unroll
            for (int j = 0; j < 4; ++j) acc[m][n][j] = 0.0f;

    const int nt = K >> 5;

    // prologue: stage k-tile 0 into buf 0
    {
#pragma unroll
        for (int s = 0; s < 2; ++s) {
            int row = bm + (s << 6) + srow;
            const u16* src = (0 < ka0) ? (A0 + (size_t)row * lda0 + scol)
                                       : (A1 + (size_t)row * lda1 + scol);
            gl_lds16(src, (char*)&lds[0][0][0] + (s << 12) + (w << 10));
            int rowb = bn + (s << 6) + srow;
            gl_lds16(Wt + (size_t)rowb * K + scol,
                     (char*)&lds[0][1][0] + (s << 12) + (w << 10));
        }
    }
    __syncthreads();

    const int ra = (wr << 6) + (l & 15);
    const int rb = (wc << 6) + (l & 15);
    const int kk = (l >> 4) << 3;

    for (int kt = 0; kt < nt; ++kt) {
        if (kt + 1 < nt) {   // stage next tile into the other buffer
            const int k0 = (kt + 1) << 5;
            const int buf = (kt + 1) & 1;
#pragma unroll
            for (int s = 0; s < 2; ++s) {
                int row = bm + (s << 6) + srow;
                const u16* src = (k0 < ka0)
                    ? (A0 + (size_t)row * lda0 + k0 + scol)
                    : (A1 + (size_t)row * lda1 + (k0 - ka0) + scol);
                gl_lds16(src, (char*)&lds[buf][0][0] + (s << 12) + (w << 10));
                int rowb = bn + (s << 6) + srow;
                gl_lds16(Wt + (size_t)rowb * K + k0 + scol,
                         (char*)&lds[buf][1][0] + (s << 12) + (w << 10));
            }
        }
        const u16* At = &lds[kt & 1][0][0];
        const u16* Bt = &lds[kt & 1][1][0];
        bf16x8 af[4], bg[4];
#pragma unroll
        for (int m = 0; m < 4; ++m)
            af[m] = *(const bf16x8*)(At + ((ra + (m << 4)) << 5) + kk);
#pragma unroll
        for (int n = 0; n < 4; ++n)
            bg[n] = *(const bf16x8*)(Bt + ((rb + (n << 4)) << 5) + kk);
#pragma unroll
        for (int m = 0; m < 4; ++m)
#pragma unroll
            for (int n = 0; n < 4; ++n)
                acc[m][n] = __builtin_amdgcn_mfma_f32_16x16x32_bf16(af[m], bg[n], acc[m][n], 0, 0, 0);
        __syncthreads();
    }

    // epilogue
    const int rl = (wr << 6) + ((l >> 4) << 2);
    const int cl = (wc << 6) + (l & 15);
#pragma unroll
    for (int n = 0; n < 4; ++n) {
        const int col = bn + cl + (n << 4);
        float bv = 0.0f;
        if (bias0) bv = (col < bsplit) ? bias0[col] : bias1[col - bsplit];
#pragma unroll
        for (int m = 0; m < 4; ++m) {
#pragma unroll
            for (int j = 0; j < 4; ++j) {
                const int row = bm + rl + (m << 4) + j;
                float v = acc[m][n][j] + bv;
                if (ACT == 1) v = fmaxf(v, 0.0f);
                if (ACT == 2) v = 1.0f / (1.0f + __expf(-v));
                if (Cf && col >= cfcol0) Cf[(size_t)row * ldcf + col] = v;
                if (Cb && col >= cbcol0) Cb[(size_t)row * ldcb + (col - cbcol0)] = f2bf(v);
            }
        }
    }
}

// ---- pred = (user .* item_table[i_idx]) @ pr_W + pr_b   (one wave per row)
__global__ void k_pred(const u16* __restrict__ user_bf, const int* __restrict__ i_idx,
                       const float* __restrict__ item_table, const float* __restrict__ pr_W,
                       const float* __restrict__ pr_b, float* __restrict__ out) {
    int gw = (blockIdx.x * 256 + threadIdx.x) >> 6;   // row
    int l = threadIdx.x & 63;
    if (gw >= NB) return;
    int it = i_idx[gw];
    int d = l * 4;
    ushort4 u4 = *(const ushort4*)(user_bf + (size_t)gw * 256 + d);
    float4 iv = *(const float4*)(item_table + (size_t)it * 256 + d);
    float4 w0 = *(const float4*)(pr_W + d * 2);       // rows d, d+1
    float4 w1 = *(const float4*)(pr_W + d * 2 + 4);   // rows d+2, d+3
    float p0 = bf2f(u4.x) * iv.x, p1 = bf2f(u4.y) * iv.y;
    float p2 = bf2f(u4.z) * iv.z, p3 = bf2f(u4.w) * iv.w;
    float s0 = p0 * w0.x + p1 * w0.z + p2 * w1.x + p3 * w1.z;
    float s1 = p0 * w0.y + p1 * w0.w + p2 * w1.y + p3 * w1.w;
#pragma unroll
    for (int off = 32; off; off >>= 1) {
        s0 += __shfl_down(s0, off);
        s1 += __shfl_down(s1, off);
    }
    if (l == 0) {
        out[(size_t)gw * 2]     = s0 + pr_b[0];
        out[(size_t)gw * 2 + 1] = s1 + pr_b[1];
    }
}

// ---- cls = hidden @ cl2_W + cl2_b  (hidden bf16 [B][128], one wave per row)
__global__ void k_cls(const u16* __restrict__ hidden, const float* __restrict__ cl2_W,
                      const float* __restrict__ cl2_b, float* __restrict__ out) {
    int gw = (blockIdx.x * 256 + threadIdx.x) >> 6;
    int l = threadIdx.x & 63;
    if (gw >= NB) return;
    int d = l * 2;
    ushort2 h2 = *(const ushort2*)(hidden + (size_t)gw * 128 + d);
    float4 w = *(const float4*)(cl2_W + d * 2);   // rows d, d+1
    float h0 = bf2f(h2.x), h1 = bf2f(h2.y);
    float s0 = h0 * w.x + h1 * w.z;
    float s1 = h0 * w.y + h1 * w.w;
#pragma unroll
    for (int off = 32; off; off >>= 1) {
        s0 += __shfl_down(s0, off);
        s1 += __shfl_down(s1, off);
    }
    if (l == 0) {
        out[(size_t)gw * 2]     = s0 + cl2_b[0];
        out[(size_t)gw * 2 + 1] = s1 + cl2_b[1];
    }
}

extern "C" void kernel_launch(void* const* d_in, const int* in_sizes, int n_in,
                              void* d_out, int out_size, void* d_ws, size_t ws_size,
                              hipStream_t stream) {
    const int* s_u = (const int*)d_in[0];
    const int* t_u = (const int*)d_in[1];
    const int* s_i = (const int*)d_in[2];
    const int* t_i = (const int*)d_in[3];
    const float* s_user_table = (const float*)d_in[4];
    const float* t_user_table = (const float*)d_in[5];
    const float* s_item_table = (const float*)d_in[6];
    const float* t_item_table = (const float*)d_in[7];
    const float* es_W = (const float*)d_in[8];
    const float* es_b = (const float*)d_in[9];
    const float* et_W = (const float*)d_in[10];
    const float* et_b = (const float*)d_in[11];
    const float* ec_W = (const float*)d_in[12];
    const float* ec_b = (const float*)d_in[13];
    const float* adj  = (const float*)d_in[14];
    const float* cl1_W = (const float*)d_in[15];
    const float* cl1_b = (const float*)d_in[16];
    const float* cl2_W = (const float*)d_in[17];
    const float* cl2_b = (const float*)d_in[18];
    const float* st_W = (const float*)d_in[19];
    const float* st_b = (const float*)d_in[20];
    const float* tt_W = (const float*)d_in[21];
    const float* tt_b = (const float*)d_in[22];
    const float* sp_W = (const float*)d_in[23];
    const float* sp_b = (const float*)d_in[24];
    const float* tp_W = (const float*)d_in[25];
    const float* tp_b = (const float*)d_in[26];

    float* out = (float*)d_out;
    float* o_spred = out;
    float* o_tpred = o_spred + (size_t)NB * 2;
    float* o_scls  = o_tpred + (size_t)NB * 2;
    float* o_tcls  = o_scls + (size_t)NB * 2;
    float* o_sinp  = o_tcls + (size_t)NB * 2;
    float* o_tinp  = o_sinp + (size_t)NB * 512;
    float* o_scau  = o_tinp + (size_t)NB * 512;
    float* o_tcau  = o_scau + (size_t)NB * 512;
    float* o_adjt  = o_tcau + (size_t)NB * 512;

    // workspace carve-up (bf16 buffers reused across branches): ~186 MB
    char* wp = (char*)d_ws;
    u16* adjT   = (u16*)wp; wp += (size_t)512 * 512 * 2;
    u16* W1t_s  = (u16*)wp; wp += (size_t)512 * 256 * 2;   // [es|ec] transposed
    u16* W1t_t  = (u16*)wp; wp += (size_t)512 * 256 * 2;
    u16* trWt_s = (u16*)wp; wp += (size_t)256 * 512 * 2;
    u16* trWt_t = (u16*)wp; wp += (size_t)256 * 512 * 2;
    u16* cl1Wt  = (u16*)wp; wp += (size_t)128 * 256 * 2;
    u16* attr   = (u16*)wp; wp += (size_t)NB * 256 * 2;
    u16* X1     = (u16*)wp; wp += (size_t)NB * 512 * 2;    // [emb | c_emb]
    u16* prefb  = (u16*)wp; wp += (size_t)NB * 256 * 2;
    u16* userb  = (u16*)wp; wp += (size_t)NB * 256 * 2;
    u16* hidden = (u16*)wp; wp += (size_t)NB * 128 * 2;

    // weight prep
    k_adj<<<1024, 256, 0, stream>>>(adj, o_adjt, adjT);
    k_castT<<<256, 256, 0, stream>>>(W1t_s,         es_W, 256, 256);
    k_castT<<<256, 256, 0, stream>>>(W1t_s + 65536, ec_W, 256, 256);
    k_castT<<<256, 256, 0, stream>>>(W1t_t,         et_W, 256, 256);
    k_castT<<<256, 256, 0, stream>>>(W1t_t + 65536, ec_W, 256, 256);
    k_castT<<<512, 256, 0, stream>>>(trWt_s, st_W, 512, 256);
    k_castT<<<512, 256, 0, stream>>>(trWt_t, tt_W, 512, 256);
    k_castT<<<128, 256, 0, stream>>>(cl1Wt, cl1_W, 256, 128);

    for (int br = 0; br < 2; ++br) {
        const int* u_idx = br ? t_u : s_u;
        const int* i_idx = br ? t_i : s_i;
        const float* utab = br ? t_user_table : s_user_table;
        const float* itab = br ? t_item_table : s_item_table;
        const u16* W1t  = br ? W1t_t : W1t_s;
        const u16* trWt = br ? trWt_t : trWt_s;
        const float* e_b  = br ? et_b : es_b;
        const float* tr_b = br ? tt_b : st_b;
        const float* p_W  = br ? tp_W : sp_W;
        const float* p_b  = br ? tp_b : sp_b;
        float* o_pred = br ? o_tpred : o_spred;
        float* o_cls  = br ? o_tcls  : o_scls;
        float* o_inp  = br ? o_tinp  : o_sinp;
        float* o_cau  = br ? o_tcau  : o_scau;

        // gather attr -> inp[:, :256] (f32) + attr (bf16)
        k_gather_user<<<16384, 256, 0, stream>>>(u_idx, utab, o_inp, attr);

        // G1: [emb|c_emb] = relu(attr @ [eW|ecW] + [eb|ecb]); f32 c_emb -> inp[:,256:]
        k_gemm<1><<<dim3(512, 4), 256, 0, stream>>>(
            attr, 256, 256, attr, 256, W1t, 256,
            e_b, ec_b, 256,
            o_inp, 512, 256,
            X1, 512, 0);

        // G2: causal = [attr|c_emb] @ adj_t ; f32 -> out, cols>=256 -> pref (bf16)
        k_gemm<0><<<dim3(512, 4), 256, 0, stream>>>(
            attr, 256, 256, X1 + 256, 512, adjT, 512,
            nullptr, nullptr, 0,
            o_cau, 512, 0,
            prefb, 256, 256);

        // G3: user = [emb|pref] @ tr_W + tr_b  (bf16)
        k_gemm<0><<<dim3(512, 2), 256, 0, stream>>>(
            X1, 512, 256, prefb, 256, trWt, 512,
            tr_b, nullptr, 1 << 30,
            nullptr, 0, 0,
            userb, 256, 0);

        // G4: hidden = sigmoid(c_emb @ cl1_W + cl1_b)  (bf16)
        k_gemm<2><<<dim3(512, 1), 256, 0, stream>>>(
            X1 + 256, 512, 256, X1, 512, cl1Wt, 256,
            cl1_b, nullptr, 1 << 30,
            nullptr, 0, 0,
            hidden, 128, 0);

        // pred = (user .* item) @ p_W + p_b   (item gathered in-kernel)
        k_pred<<<16384, 256, 0, stream>>>(userb, i_idx, itab, p_W, p_b, o_pred);

        // cls = hidden @ cl2_W + cl2_b
        k_cls<<<16384, 256, 0, stream>>>(hidden, cl2_W, cl2_b, o_cls);
    }
}